// Round 15
// baseline (44.092 us; speedup 1.0000x reference)
//
#include <hip/hip_runtime.h>
#include <math.h>

typedef float f32x2 __attribute__((ext_vector_type(2)));
typedef float f32x4 __attribute__((ext_vector_type(4)));

#define TWO_PI 6.283185307179586f
#define SMOOTH 0.1f
#define SPW 8                  // stations per WAVE
#define WAVES 4
#define BLOCK 256
#define SPB (SPW * WAVES)      // 32 stations; slab = 128*T bytes (line-integral)
#define NPAIR 3                // column pairs per thread
#define TP_ROWS 192            // basis table rows (>= 64+128)
#define TP_BYTES (TP_ROWS * 16 * 4)

__device__ __forceinline__ f32x2 sp2(float x) { f32x2 r; r.x = x; r.y = x; return r; }
__device__ __forceinline__ f32x2 mk2(float a, float b) { f32x2 r; r.x = a; r.y = b; return r; }
__device__ __forceinline__ float rlane(float v, int l) {
    return __uint_as_float((unsigned)__builtin_amdgcn_readlane((int)__float_as_uint(v), l));
}

// ---------------------------------------------------------------------------
// Kernel A (R9, proven): per-station coefficients + pair-interleaved basis.
// coef[i][12]  = { c, m, A0,B0, A1,B1, A2,B2, A3,B3, 0,0 }
// tableP[p][16]= { s0(2p),s0(2p+1), s1.., s2.., s3..,  c0(2p),c0(2p+1), c1.., c2.., c3.. }
// ---------------------------------------------------------------------------
__global__ void coef_table_kernel(
    const float* __restrict__ time_vector,
    const float* __restrict__ constant_offset,
    const float* __restrict__ linear_trend,
    const float* __restrict__ amps,      // [N][4]
    const float* __restrict__ phs,       // [N][4]
    const float* __restrict__ wgt,       // [N][K]
    const float* __restrict__ periods,   // [4]
    const int*   __restrict__ nbidx,     // [N][K]
    float* __restrict__ tableP,          // [TP_ROWS][16]
    float* __restrict__ coef,            // [N][12]
    int N, int T, int K)
{
    int i = blockIdx.x * blockDim.x + threadIdx.x;

    if (i < T) {
        float tv = time_vector[i];
        const int p = i >> 1, o = i & 1;
        float* row = tableP + p * 16;
        #pragma unroll
        for (int f = 0; f < 4; ++f) {
            float ang = (TWO_PI / periods[f]) * tv;
            row[2 * f + o]     = __sinf(ang);
            row[8 + 2 * f + o] = __cosf(ang);
        }
    }

    if (i < N) {
        float4 a = reinterpret_cast<const float4*>(amps)[i];
        float4 p = reinterpret_cast<const float4*>(phs)[i];

        int   nb[5]; float w[5];
        __builtin_memcpy(nb, nbidx + (size_t)i * K, 5 * sizeof(int));
        __builtin_memcpy(w,  wgt   + (size_t)i * K, 5 * sizeof(float));

        float av0 = 0.f, av1 = 0.f, av2 = 0.f, av3 = 0.f;
        float pv0 = 0.f, pv1 = 0.f, pv2 = 0.f, pv3 = 0.f;
        #pragma unroll
        for (int k = 0; k < 5; ++k) {
            float4 na = reinterpret_cast<const float4*>(amps)[nb[k]];
            float4 np = reinterpret_cast<const float4*>(phs)[nb[k]];
            av0 += w[k] * na.x; av1 += w[k] * na.y; av2 += w[k] * na.z; av3 += w[k] * na.w;
            pv0 += w[k] * np.x; pv1 += w[k] * np.y; pv2 += w[k] * np.z; pv3 += w[k] * np.w;
        }
        float sa0 = (1.0f - SMOOTH) * a.x + SMOOTH * av0;
        float sa1 = (1.0f - SMOOTH) * a.y + SMOOTH * av1;
        float sa2 = (1.0f - SMOOTH) * a.z + SMOOTH * av2;
        float sa3 = (1.0f - SMOOTH) * a.w + SMOOTH * av3;
        float sp0 = (1.0f - SMOOTH) * p.x + SMOOTH * pv0;
        float sp1 = (1.0f - SMOOTH) * p.y + SMOOTH * pv1;
        float sp2 = (1.0f - SMOOTH) * p.z + SMOOTH * pv2;
        float sp3 = (1.0f - SMOOTH) * p.w + SMOOTH * pv3;

        float4 vA, vB, vC;
        vA.x = constant_offset[i]; vA.y = linear_trend[i];
        vA.z = sa0 * __cosf(sp0);  vA.w = sa0 * __sinf(sp0);
        vB.x = sa1 * __cosf(sp1);  vB.y = sa1 * __sinf(sp1);
        vB.z = sa2 * __cosf(sp2);  vB.w = sa2 * __sinf(sp2);
        vC.x = sa3 * __cosf(sp3);  vC.y = sa3 * __sinf(sp3);
        vC.z = 0.f; vC.w = 0.f;
        float4* cp = reinterpret_cast<float4*>(coef + (size_t)i * 12);
        cp[0] = vA; cp[1] = vB; cp[2] = vC;
    }
}

// ---------------------------------------------------------------------------
// Writer v15 = v14's slab + register-batched nt full-line sweep, with ALL
// transcendentals and the neighbor gather removed (fed by kernel A).
// Writer per block: 3 float4 coef loads/lane + 12 float4 table loads +
// pk-fma emit -> LDS -> batched nt dwordx4 sweep.
// ---------------------------------------------------------------------------
template<int TT>
__global__ __launch_bounds__(BLOCK) void writer_v15(
    const float* __restrict__ time_vector,
    const float* __restrict__ tableP,    // [TP_ROWS][16]
    const float* __restrict__ coef,      // [N][12]
    float* __restrict__ out,             // [N][T]
    int N, int T_rt)
{
    const int T = (TT > 0) ? TT : T_rt;
    extern __shared__ float slab[];      // SPB * T floats

    const int tid    = threadIdx.x;
    const int wave   = tid >> 6;
    const int lane   = tid & 63;
    const int bbase  = blockIdx.x * SPB;
    const int wbase  = bbase + wave * SPW;

    if (bbase >= N) return;
    int bsend = N - bbase; if (bsend > SPB) bsend = SPB;

    // ---- coefs: per-lane float4 loads for station wbase+(lane&7) ----
    int sid = wbase + (lane & (SPW - 1));
    if (sid >= N) sid = N - 1;
    const float4* cp = reinterpret_cast<const float4*>(coef + (size_t)sid * 12);
    float4 k0 = cp[0];   // c, m, A0, B0
    float4 k1 = cp[1];   // A1, B1, A2, B2
    float4 k2 = cp[2];   // A3, B3, -, -

    // ---- basis: from table (no trig) ----
    const int t0 = 2 * lane;
    f32x2 tv[NPAIR];
    f32x2 bs[NPAIR][4], bc[NPAIR][4];
    bool full[NPAIR], any[NPAIR];

    #pragma unroll
    for (int q = 0; q < NPAIR; ++q) {
        const int t = t0 + 128 * q;
        const bool v0 = (t < T), v1 = (t + 1 < T);
        any[q] = v0; full[q] = v1;
        float ta = v0 ? time_vector[t]     : 0.f;
        float tb = v1 ? time_vector[t + 1] : 0.f;
        tv[q] = mk2(ta, tb);

        const float4* rp = reinterpret_cast<const float4*>(tableP + (size_t)(lane + 64 * q) * 16);
        float4 r0 = rp[0];   // s0a s0b s1a s1b
        float4 r1 = rp[1];   // s2a s2b s3a s3b
        float4 r2 = rp[2];   // c0a c0b c1a c1b
        float4 r3 = rp[3];   // c2a c2b c3a c3b
        bs[q][0] = mk2(r0.x, r0.y); bs[q][1] = mk2(r0.z, r0.w);
        bs[q][2] = mk2(r1.x, r1.y); bs[q][3] = mk2(r1.z, r1.w);
        bc[q][0] = mk2(r2.x, r2.y); bc[q][1] = mk2(r2.z, r2.w);
        bc[q][2] = mk2(r3.x, r3.y); bc[q][3] = mk2(r3.z, r3.w);
    }

    if (bsend == SPB) {
        // ---- emit 8 station rows to LDS ----
        float* wrows = slab + (size_t)(wave * SPW) * T;

        #pragma unroll
        for (int j = 0; j < SPW; ++j) {
            float sc  = rlane(k0.x, j), sm  = rlane(k0.y, j);
            float sA0 = rlane(k0.z, j), sB0 = rlane(k0.w, j);
            float sA1 = rlane(k1.x, j), sB1 = rlane(k1.y, j);
            float sA2 = rlane(k1.z, j), sB2 = rlane(k1.w, j);
            float sA3 = rlane(k2.x, j), sB3 = rlane(k2.y, j);
            float* lrow = wrows + j * T;

            #pragma unroll
            for (int q = 0; q < NPAIR; ++q) {
                f32x2 sig = sp2(sc) + sp2(sm) * tv[q];
                sig += sp2(sA0) * bs[q][0] + sp2(sB0) * bc[q][0];
                sig += sp2(sA1) * bs[q][1] + sp2(sB1) * bc[q][1];
                sig += sp2(sA2) * bs[q][2] + sp2(sB2) * bc[q][2];
                sig += sp2(sA3) * bs[q][3] + sp2(sB3) * bc[q][3];
                const int t = t0 + 128 * q;
                if (full[q]) { lrow[t] = sig.x; lrow[t + 1] = sig.y; }
                else if (any[q]) { lrow[t] = sig.x; }
            }
        }

        __syncthreads();

        // ---- register-batched nt full-line sweep (v14) ----
        const f32x4* lsrc = reinterpret_cast<const f32x4*>(slab);
        f32x4* gdst = reinterpret_cast<f32x4*>(out + (size_t)bbase * T);

        if (TT == 365) {
            f32x4 v0_ = lsrc[tid];          f32x4 v1_ = lsrc[tid + 256];
            f32x4 v2_ = lsrc[tid + 512];    f32x4 v3_ = lsrc[tid + 768];
            f32x4 v4_ = lsrc[tid + 1024];   f32x4 v5_ = lsrc[tid + 1280];
            f32x4 v6_ = lsrc[tid + 1536];   f32x4 v7_ = lsrc[tid + 1792];
            f32x4 v8_ = lsrc[tid + 2048];   f32x4 v9_ = lsrc[tid + 2304];
            f32x4 va_ = lsrc[tid + 2560];
            const bool extra = (tid < 104);
            f32x4 vb_;
            if (extra) vb_ = lsrc[tid + 2816];

            __builtin_nontemporal_store(v0_, gdst + tid);
            __builtin_nontemporal_store(v1_, gdst + tid + 256);
            __builtin_nontemporal_store(v2_, gdst + tid + 512);
            __builtin_nontemporal_store(v3_, gdst + tid + 768);
            __builtin_nontemporal_store(v4_, gdst + tid + 1024);
            __builtin_nontemporal_store(v5_, gdst + tid + 1280);
            __builtin_nontemporal_store(v6_, gdst + tid + 1536);
            __builtin_nontemporal_store(v7_, gdst + tid + 1792);
            __builtin_nontemporal_store(v8_, gdst + tid + 2048);
            __builtin_nontemporal_store(v9_, gdst + tid + 2304);
            __builtin_nontemporal_store(va_, gdst + tid + 2560);
            if (extra) __builtin_nontemporal_store(vb_, gdst + tid + 2816);
        } else {
            const int nch = (SPB * T) >> 2;
            for (int i = tid; i < nch; i += BLOCK) {
                f32x4 v = lsrc[i];
                __builtin_nontemporal_store(v, gdst + i);
            }
        }
    } else {
        // ---- tail path: direct cached stores ----
        int send = N - wbase; if (send > SPW) send = SPW;
        if (send <= 0) return;
        float* obase = out + (size_t)wbase * T;
        for (int j = 0; j < send; ++j) {
            float sc  = rlane(k0.x, j), sm  = rlane(k0.y, j);
            float sA0 = rlane(k0.z, j), sB0 = rlane(k0.w, j);
            float sA1 = rlane(k1.x, j), sB1 = rlane(k1.y, j);
            float sA2 = rlane(k1.z, j), sB2 = rlane(k1.w, j);
            float sA3 = rlane(k2.x, j), sB3 = rlane(k2.y, j);
            float* orow = obase + (size_t)j * T;
            #pragma unroll
            for (int q = 0; q < NPAIR; ++q) {
                f32x2 sig = sp2(sc) + sp2(sm) * tv[q];
                sig += sp2(sA0) * bs[q][0] + sp2(sB0) * bc[q][0];
                sig += sp2(sA1) * bs[q][1] + sp2(sB1) * bc[q][1];
                sig += sp2(sA2) * bs[q][2] + sp2(sB2) * bc[q][2];
                sig += sp2(sA3) * bs[q][3] + sp2(sB3) * bc[q][3];
                const int t = t0 + 128 * q;
                if (full[q]) { orow[t] = sig.x; orow[t + 1] = sig.y; }
                else if (any[q]) { orow[t] = sig.x; }
            }
        }
    }
}

extern "C" void kernel_launch(void* const* d_in, const int* in_sizes, int n_in,
                              void* d_out, int out_size, void* d_ws, size_t ws_size,
                              hipStream_t stream)
{
    const float* time_vector     = (const float*)d_in[0];
    const float* constant_offset = (const float*)d_in[1];
    const float* linear_trend    = (const float*)d_in[2];
    const float* amps            = (const float*)d_in[3];
    const float* phs             = (const float*)d_in[4];
    const float* wgt             = (const float*)d_in[5];
    const float* periods         = (const float*)d_in[6];
    const int*   nbidx           = (const int*)d_in[7];

    int T = in_sizes[0];
    int N = in_sizes[1];
    int K = in_sizes[5] / N;
    float* out = (float*)d_out;

    float* tableP = (float*)d_ws;                      // 12 KB
    float* coef   = (float*)((char*)d_ws + TP_BYTES);  // 4.8 MB

    int threads = 256;
    int workA = (N > T) ? N : T;
    int gridA = (workA + threads - 1) / threads;
    coef_table_kernel<<<gridA, threads, 0, stream>>>(
        time_vector, constant_offset, linear_trend, amps, phs, wgt,
        periods, nbidx, tableP, coef, N, T, K);

    int grid = (N + SPB - 1) / SPB;
    size_t shmem = (size_t)SPB * T * sizeof(float);
    if (T == 365) {
        writer_v15<365><<<grid, BLOCK, shmem, stream>>>(
            time_vector, tableP, coef, out, N, T);
    } else {
        writer_v15<0><<<grid, BLOCK, shmem, stream>>>(
            time_vector, tableP, coef, out, N, T);
    }
}

// Round 16
// 43.751 us; speedup vs baseline: 1.0078x; 1.0078x over previous
//
#include <hip/hip_runtime.h>
#include <math.h>

typedef float f32x2 __attribute__((ext_vector_type(2)));
typedef float f32x4 __attribute__((ext_vector_type(4)));

#define TWO_PI 6.283185307179586f
#define SMOOTH 0.1f
#define SPW 8                  // rows per wave per slab
#define WAVES 4
#define BLOCK 256
#define SPB 32                 // stations per slab; slab = 128*T bytes (line-integral)
#define SLABS 4                // slabs per block (pipelined)
#define NPAIR 3                // column pairs per thread

__device__ __forceinline__ f32x2 sp2(float x) { f32x2 r; r.x = x; r.y = x; return r; }
__device__ __forceinline__ float rlane(float v, int l) {
    return __uint_as_float((unsigned)__builtin_amdgcn_readlane((int)__float_as_uint(v), l));
}
// Barrier WITHOUT vmcnt drain: only LDS (lgkm) ordering. Global nt stores
// stay in flight across it — emit of slab s+1 overlaps retirement of slab
// s's stores. (__syncthreads would force s_waitcnt vmcnt(0): the drain that
// serialized v14's per-block pipeline.)
__device__ __forceinline__ void barrier_lgkm() {
    asm volatile("s_waitcnt lgkmcnt(0)\ns_barrier" ::: "memory");
}

// v16 = v14 (slab + batched nt full-line sweep) restructured as a 4-slab
// in-block pipeline with zero in-loop vmcnt drains:
//   prologue: coefs for ALL 4 slabs in registers (lane l -> slab (l>>3)&3,
//             row l&7; 4x less redundant gather than v14), basis trig once
//   loop:     emit -> lgkm-barrier -> ds_read batch + nt stores (no wait)
//             -> lgkm-barrier -> next emit (stores retire in background)
template<int TT>
__global__ __launch_bounds__(BLOCK) void fused_v16(
    const float* __restrict__ time_vector,
    const float* __restrict__ constant_offset,
    const float* __restrict__ linear_trend,
    const float* __restrict__ amps,      // [N][4]
    const float* __restrict__ phs,       // [N][4]
    const float* __restrict__ wgt,       // [N][K]
    const float* __restrict__ periods,   // [4]
    const int*   __restrict__ nbidx,     // [N][K]
    float* __restrict__ out,             // [N][T]
    int N, int T_rt, int K, int nslab)
{
    const int T = (TT > 0) ? TT : T_rt;
    extern __shared__ float slab[];      // SPB * T floats

    const int tid   = threadIdx.x;
    const int wave  = tid >> 6;
    const int lane  = tid & 63;
    const int slab0 = blockIdx.x * SLABS;
    if (slab0 >= nslab) return;

    // ---- Prologue A: coefs for station (slab0+sgrp, wave, jrow) ----
    const int sgrp = (lane >> 3) & (SLABS - 1);   // which of my 4 slabs
    const int jrow = lane & 7;                    // row within wave section
    int sid = (slab0 + sgrp) * SPB + wave * SPW + jrow;
    if (sid >= N) sid = N - 1;

    float4 a = reinterpret_cast<const float4*>(amps)[sid];
    float4 p = reinterpret_cast<const float4*>(phs)[sid];

    int   nb[5]; float w[5];
    __builtin_memcpy(nb, nbidx + (size_t)sid * K, 5 * sizeof(int));
    __builtin_memcpy(w,  wgt   + (size_t)sid * K, 5 * sizeof(float));

    float av0 = 0.f, av1 = 0.f, av2 = 0.f, av3 = 0.f;
    float pv0 = 0.f, pv1 = 0.f, pv2 = 0.f, pv3 = 0.f;
    #pragma unroll
    for (int k = 0; k < 5; ++k) {
        float4 na = reinterpret_cast<const float4*>(amps)[nb[k]];
        float4 np = reinterpret_cast<const float4*>(phs)[nb[k]];
        av0 += w[k] * na.x; av1 += w[k] * na.y; av2 += w[k] * na.z; av3 += w[k] * na.w;
        pv0 += w[k] * np.x; pv1 += w[k] * np.y; pv2 += w[k] * np.z; pv3 += w[k] * np.w;
    }
    float sa0 = (1.0f - SMOOTH) * a.x + SMOOTH * av0;
    float sa1 = (1.0f - SMOOTH) * a.y + SMOOTH * av1;
    float sa2 = (1.0f - SMOOTH) * a.z + SMOOTH * av2;
    float sa3 = (1.0f - SMOOTH) * a.w + SMOOTH * av3;
    float sp0 = (1.0f - SMOOTH) * p.x + SMOOTH * pv0;
    float sp1 = (1.0f - SMOOTH) * p.y + SMOOTH * pv1;
    float sp2v = (1.0f - SMOOTH) * p.z + SMOOTH * pv2;
    float sp3 = (1.0f - SMOOTH) * p.w + SMOOTH * pv3;

    float cc = constant_offset[sid];
    float cm = linear_trend[sid];
    float cA0 = sa0 * __cosf(sp0),  cB0 = sa0 * __sinf(sp0);
    float cA1 = sa1 * __cosf(sp1),  cB1 = sa1 * __sinf(sp1);
    float cA2 = sa2 * __cosf(sp2v), cB2 = sa2 * __sinf(sp2v);
    float cA3 = sa3 * __cosf(sp3),  cB3 = sa3 * __sinf(sp3);

    // ---- Prologue B: basis (3 column pairs per thread), in registers ----
    const float w0 = TWO_PI / periods[0];
    const float w1 = TWO_PI / periods[1];
    const float w2 = TWO_PI / periods[2];
    const float w3 = TWO_PI / periods[3];

    f32x2 tv[NPAIR];
    f32x2 bs[NPAIR][4], bc[NPAIR][4];
    bool full[NPAIR], any[NPAIR];
    const int t0 = 2 * lane;

    #pragma unroll
    for (int q = 0; q < NPAIR; ++q) {
        const int t = t0 + 128 * q;
        const bool v0 = (t < T), v1 = (t + 1 < T);
        any[q] = v0; full[q] = v1;
        float ta = v0 ? time_vector[t]     : 0.f;
        float tb = v1 ? time_vector[t + 1] : 0.f;
        f32x2 tvp; tvp.x = ta; tvp.y = tb;
        tv[q] = tvp;
        #pragma unroll
        for (int f = 0; f < 4; ++f) {
            const float wf = (f == 0) ? w0 : (f == 1) ? w1 : (f == 2) ? w2 : w3;
            f32x2 s, c;
            s.x = __sinf(wf * ta); s.y = __sinf(wf * tb);
            c.x = __cosf(wf * ta); c.y = __cosf(wf * tb);
            bs[q][f] = s; bc[q][f] = c;
        }
    }

    float* wrows = slab + (size_t)(wave * SPW) * T;
    const f32x4* lsrc = reinterpret_cast<const f32x4*>(slab);

    // ---- Pipelined slab loop: no vmcnt drain anywhere inside ----
    #pragma unroll
    for (int s = 0; s < SLABS; ++s) {
        const int si = slab0 + s;
        if (si >= nslab) break;
        const int bbase = si * SPB;
        const bool fullslab = (bbase + SPB <= N);   // block-uniform

        if (fullslab) {
            // emit 8 rows of this slab (coefs broadcast from lane (s<<3)|j)
            #pragma unroll
            for (int j = 0; j < SPW; ++j) {
                const int src = (s << 3) | j;
                float sc  = rlane(cc,  src), sm  = rlane(cm,  src);
                float sA0 = rlane(cA0, src), sB0 = rlane(cB0, src);
                float sA1 = rlane(cA1, src), sB1 = rlane(cB1, src);
                float sA2 = rlane(cA2, src), sB2 = rlane(cB2, src);
                float sA3 = rlane(cA3, src), sB3 = rlane(cB3, src);
                float* lrow = wrows + j * T;

                #pragma unroll
                for (int q = 0; q < NPAIR; ++q) {
                    f32x2 sig = sp2(sc) + sp2(sm) * tv[q];
                    sig += sp2(sA0) * bs[q][0] + sp2(sB0) * bc[q][0];
                    sig += sp2(sA1) * bs[q][1] + sp2(sB1) * bc[q][1];
                    sig += sp2(sA2) * bs[q][2] + sp2(sB2) * bc[q][2];
                    sig += sp2(sA3) * bs[q][3] + sp2(sB3) * bc[q][3];
                    const int t = t0 + 128 * q;
                    if (full[q]) { lrow[t] = sig.x; lrow[t + 1] = sig.y; }
                    else if (any[q]) { lrow[t] = sig.x; }
                }
            }

            barrier_lgkm();    // LDS visible; stores from slab s-1 still in flight

            // batched full-line nt sweep of the slab
            f32x4* gdst = reinterpret_cast<f32x4*>(out + (size_t)bbase * T);
            if (TT == 365) {
                f32x4 v0_ = lsrc[tid];          f32x4 v1_ = lsrc[tid + 256];
                f32x4 v2_ = lsrc[tid + 512];    f32x4 v3_ = lsrc[tid + 768];
                f32x4 v4_ = lsrc[tid + 1024];   f32x4 v5_ = lsrc[tid + 1280];
                f32x4 v6_ = lsrc[tid + 1536];   f32x4 v7_ = lsrc[tid + 1792];
                f32x4 v8_ = lsrc[tid + 2048];   f32x4 v9_ = lsrc[tid + 2304];
                f32x4 va_ = lsrc[tid + 2560];
                const bool extra = (tid < 104);
                f32x4 vb_;
                if (extra) vb_ = lsrc[tid + 2816];

                __builtin_nontemporal_store(v0_, gdst + tid);
                __builtin_nontemporal_store(v1_, gdst + tid + 256);
                __builtin_nontemporal_store(v2_, gdst + tid + 512);
                __builtin_nontemporal_store(v3_, gdst + tid + 768);
                __builtin_nontemporal_store(v4_, gdst + tid + 1024);
                __builtin_nontemporal_store(v5_, gdst + tid + 1280);
                __builtin_nontemporal_store(v6_, gdst + tid + 1536);
                __builtin_nontemporal_store(v7_, gdst + tid + 1792);
                __builtin_nontemporal_store(v8_, gdst + tid + 2048);
                __builtin_nontemporal_store(v9_, gdst + tid + 2304);
                __builtin_nontemporal_store(va_, gdst + tid + 2560);
                if (extra) __builtin_nontemporal_store(vb_, gdst + tid + 2816);
            } else {
                const int nch = (SPB * T) >> 2;
                for (int i = tid; i < nch; i += BLOCK) {
                    f32x4 v = lsrc[i];
                    __builtin_nontemporal_store(v, gdst + i);
                }
            }

            barrier_lgkm();    // all waves' ds_reads done -> LDS reusable
        } else {
            // tail slab (N % SPB != 0 only): direct cached stores, no LDS
            int wfirst = bbase + wave * SPW;
            int send = N - wfirst; if (send > SPW) send = SPW;
            if (send > 0) {
                float* obase = out + (size_t)wfirst * T;
                for (int j = 0; j < send; ++j) {
                    const int src = (s << 3) | j;
                    float sc  = rlane(cc,  src), sm  = rlane(cm,  src);
                    float sA0 = rlane(cA0, src), sB0 = rlane(cB0, src);
                    float sA1 = rlane(cA1, src), sB1 = rlane(cB1, src);
                    float sA2 = rlane(cA2, src), sB2 = rlane(cB2, src);
                    float sA3 = rlane(cA3, src), sB3 = rlane(cB3, src);
                    float* orow = obase + (size_t)j * T;
                    #pragma unroll
                    for (int q = 0; q < NPAIR; ++q) {
                        f32x2 sig = sp2(sc) + sp2(sm) * tv[q];
                        sig += sp2(sA0) * bs[q][0] + sp2(sB0) * bc[q][0];
                        sig += sp2(sA1) * bs[q][1] + sp2(sB1) * bc[q][1];
                        sig += sp2(sA2) * bs[q][2] + sp2(sB2) * bc[q][2];
                        sig += sp2(sA3) * bs[q][3] + sp2(sB3) * bc[q][3];
                        const int t = t0 + 128 * q;
                        if (full[q]) { orow[t] = sig.x; orow[t + 1] = sig.y; }
                        else if (any[q]) { orow[t] = sig.x; }
                    }
                }
            }
        }
    }
}

extern "C" void kernel_launch(void* const* d_in, const int* in_sizes, int n_in,
                              void* d_out, int out_size, void* d_ws, size_t ws_size,
                              hipStream_t stream)
{
    const float* time_vector     = (const float*)d_in[0];
    const float* constant_offset = (const float*)d_in[1];
    const float* linear_trend    = (const float*)d_in[2];
    const float* amps            = (const float*)d_in[3];
    const float* phs             = (const float*)d_in[4];
    const float* wgt             = (const float*)d_in[5];
    const float* periods         = (const float*)d_in[6];
    const int*   nbidx           = (const int*)d_in[7];

    int T = in_sizes[0];
    int N = in_sizes[1];
    int K = in_sizes[5] / N;
    float* out = (float*)d_out;

    int nslab = (N + SPB - 1) / SPB;                 // 3125 @ N=100000
    int grid  = (nslab + SLABS - 1) / SLABS;         // 782
    size_t shmem = (size_t)SPB * T * sizeof(float);  // 46720 B @ T=365

    if (T == 365) {
        fused_v16<365><<<grid, BLOCK, shmem, stream>>>(
            time_vector, constant_offset, linear_trend, amps, phs, wgt,
            periods, nbidx, out, N, T, K, nslab);
    } else {
        fused_v16<0><<<grid, BLOCK, shmem, stream>>>(
            time_vector, constant_offset, linear_trend, amps, phs, wgt,
            periods, nbidx, out, N, T, K, nslab);
    }
}

// Round 17
// 35.431 us; speedup vs baseline: 1.2444x; 1.2348x over previous
//
#include <hip/hip_runtime.h>
#include <math.h>

typedef float f32x2 __attribute__((ext_vector_type(2)));
typedef float f32x4 __attribute__((ext_vector_type(4)));

#define TWO_PI 6.283185307179586f
#define SMOOTH 0.1f
#define SPW 8                  // stations per WAVE
#define WAVES 4
#define BLOCK 256
#define SPB (SPW * WAVES)      // 32 stations per block
#define NPAIR 3                // column pairs per thread

__device__ __forceinline__ f32x2 sp2(float x) { f32x2 r; r.x = x; r.y = x; return r; }
__device__ __forceinline__ float rlane(float v, int l) {
    return __uint_as_float((unsigned)__builtin_amdgcn_readlane((int)__float_as_uint(v), l));
}
// Wave-local LDS drain: no s_barrier, no vmcnt. Orders this wave's ds_write
// -> ds_read. (Wave reads only data it wrote itself.)
__device__ __forceinline__ void wait_lgkm() {
    asm volatile("s_waitcnt lgkmcnt(0)" ::: "memory");
}

// v17 = v14 with ALL block synchronization removed: the slab is WAVE-private.
// Each wave emits its own 8 rows into its own LDS region, does a wave-local
// lgkm wait (no barrier), then a register-batched nt sweep of its region.
// Waves desynchronize naturally -> the CU's store feed becomes continuous
// instead of v14's burst(48KB)/silence(prologue) alternation.
// Cost: wave region = 11680 B = 91.25 lines -> 3/365 lines per block straddle
// two store instructions (~0.8%, negligible vs R7's 50%).
template<int TT>
__global__ __launch_bounds__(BLOCK) void fused_v17(
    const float* __restrict__ time_vector,
    const float* __restrict__ constant_offset,
    const float* __restrict__ linear_trend,
    const float* __restrict__ amps,      // [N][4]
    const float* __restrict__ phs,       // [N][4]
    const float* __restrict__ wgt,       // [N][K]
    const float* __restrict__ periods,   // [4]
    const int*   __restrict__ nbidx,     // [N][K]
    float* __restrict__ out,             // [N][T]
    int N, int T_rt, int K)
{
    const int T = (TT > 0) ? TT : T_rt;
    extern __shared__ float slab[];      // SPB * T floats (per-wave regions)

    const int tid    = threadIdx.x;
    const int wave   = tid >> 6;
    const int lane   = tid & 63;
    const int wbase  = blockIdx.x * SPB + wave * SPW;

    if (wbase >= N) return;
    int send = N - wbase; if (send > SPW) send = SPW;

    // ---- Phase 1: coefs for station wbase+(lane&7), all lanes redundant ----
    int sid = wbase + (lane & (SPW - 1));
    if (sid >= N) sid = N - 1;

    float4 a = reinterpret_cast<const float4*>(amps)[sid];
    float4 p = reinterpret_cast<const float4*>(phs)[sid];

    int   nb[5]; float w[5];
    __builtin_memcpy(nb, nbidx + (size_t)sid * K, 5 * sizeof(int));
    __builtin_memcpy(w,  wgt   + (size_t)sid * K, 5 * sizeof(float));

    float av0 = 0.f, av1 = 0.f, av2 = 0.f, av3 = 0.f;
    float pv0 = 0.f, pv1 = 0.f, pv2 = 0.f, pv3 = 0.f;
    #pragma unroll
    for (int k = 0; k < 5; ++k) {
        float4 na = reinterpret_cast<const float4*>(amps)[nb[k]];
        float4 np = reinterpret_cast<const float4*>(phs)[nb[k]];
        av0 += w[k] * na.x; av1 += w[k] * na.y; av2 += w[k] * na.z; av3 += w[k] * na.w;
        pv0 += w[k] * np.x; pv1 += w[k] * np.y; pv2 += w[k] * np.z; pv3 += w[k] * np.w;
    }
    float sa0 = (1.0f - SMOOTH) * a.x + SMOOTH * av0;
    float sa1 = (1.0f - SMOOTH) * a.y + SMOOTH * av1;
    float sa2 = (1.0f - SMOOTH) * a.z + SMOOTH * av2;
    float sa3 = (1.0f - SMOOTH) * a.w + SMOOTH * av3;
    float sp0 = (1.0f - SMOOTH) * p.x + SMOOTH * pv0;
    float sp1 = (1.0f - SMOOTH) * p.y + SMOOTH * pv1;
    float sp2v = (1.0f - SMOOTH) * p.z + SMOOTH * pv2;
    float sp3 = (1.0f - SMOOTH) * p.w + SMOOTH * pv3;

    float cc = constant_offset[sid];
    float cm = linear_trend[sid];
    float cA0 = sa0 * __cosf(sp0),  cB0 = sa0 * __sinf(sp0);
    float cA1 = sa1 * __cosf(sp1),  cB1 = sa1 * __sinf(sp1);
    float cA2 = sa2 * __cosf(sp2v), cB2 = sa2 * __sinf(sp2v);
    float cA3 = sa3 * __cosf(sp3),  cB3 = sa3 * __sinf(sp3);

    // ---- Basis: 3 adjacent column pairs per thread, in registers ----
    const float w0 = TWO_PI / periods[0];
    const float w1 = TWO_PI / periods[1];
    const float w2 = TWO_PI / periods[2];
    const float w3 = TWO_PI / periods[3];

    f32x2 tv[NPAIR];
    f32x2 bs[NPAIR][4], bc[NPAIR][4];
    bool full[NPAIR], any[NPAIR];
    const int t0 = 2 * lane;

    #pragma unroll
    for (int q = 0; q < NPAIR; ++q) {
        const int t = t0 + 128 * q;
        const bool v0 = (t < T), v1 = (t + 1 < T);
        any[q] = v0; full[q] = v1;
        float ta = v0 ? time_vector[t]     : 0.f;
        float tb = v1 ? time_vector[t + 1] : 0.f;
        f32x2 tvp; tvp.x = ta; tvp.y = tb;
        tv[q] = tvp;
        #pragma unroll
        for (int f = 0; f < 4; ++f) {
            const float wf = (f == 0) ? w0 : (f == 1) ? w1 : (f == 2) ? w2 : w3;
            f32x2 s, c;
            s.x = __sinf(wf * ta); s.y = __sinf(wf * tb);
            c.x = __cosf(wf * ta); c.y = __cosf(wf * tb);
            bs[q][f] = s; bc[q][f] = c;
        }
    }

    float* wrows = slab + (size_t)(wave * SPW) * T;   // wave-private region

    if (send == SPW) {
        // ---- emit this wave's 8 rows into its private LDS region ----
        #pragma unroll
        for (int j = 0; j < SPW; ++j) {
            float sc  = rlane(cc,  j), sm  = rlane(cm,  j);
            float sA0 = rlane(cA0, j), sB0 = rlane(cB0, j);
            float sA1 = rlane(cA1, j), sB1 = rlane(cB1, j);
            float sA2 = rlane(cA2, j), sB2 = rlane(cB2, j);
            float sA3 = rlane(cA3, j), sB3 = rlane(cB3, j);
            float* lrow = wrows + j * T;

            #pragma unroll
            for (int q = 0; q < NPAIR; ++q) {
                f32x2 sig = sp2(sc) + sp2(sm) * tv[q];
                sig += sp2(sA0) * bs[q][0] + sp2(sB0) * bc[q][0];
                sig += sp2(sA1) * bs[q][1] + sp2(sB1) * bc[q][1];
                sig += sp2(sA2) * bs[q][2] + sp2(sB2) * bc[q][2];
                sig += sp2(sA3) * bs[q][3] + sp2(sB3) * bc[q][3];
                const int t = t0 + 128 * q;
                if (full[q]) { lrow[t] = sig.x; lrow[t + 1] = sig.y; }
                else if (any[q]) { lrow[t] = sig.x; }
            }
        }

        wait_lgkm();   // wave-local: my ds_writes visible to my ds_reads

        // ---- register-batched nt sweep of MY region (no barrier) ----
        // region = 8*T floats = 2*T float4 chunks (T=365 -> 730 = 11*64 + 26)
        const f32x4* lsrc = reinterpret_cast<const f32x4*>(wrows);
        f32x4* gdst = reinterpret_cast<f32x4*>(out + (size_t)wbase * T);

        if (TT == 365) {
            f32x4 v0_ = lsrc[lane];         f32x4 v1_ = lsrc[lane + 64];
            f32x4 v2_ = lsrc[lane + 128];   f32x4 v3_ = lsrc[lane + 192];
            f32x4 v4_ = lsrc[lane + 256];   f32x4 v5_ = lsrc[lane + 320];
            f32x4 v6_ = lsrc[lane + 384];   f32x4 v7_ = lsrc[lane + 448];
            f32x4 v8_ = lsrc[lane + 512];   f32x4 v9_ = lsrc[lane + 576];
            f32x4 va_ = lsrc[lane + 640];
            const bool extra = (lane < 26);
            f32x4 vb_;
            if (extra) vb_ = lsrc[lane + 704];

            __builtin_nontemporal_store(v0_, gdst + lane);
            __builtin_nontemporal_store(v1_, gdst + lane + 64);
            __builtin_nontemporal_store(v2_, gdst + lane + 128);
            __builtin_nontemporal_store(v3_, gdst + lane + 192);
            __builtin_nontemporal_store(v4_, gdst + lane + 256);
            __builtin_nontemporal_store(v5_, gdst + lane + 320);
            __builtin_nontemporal_store(v6_, gdst + lane + 384);
            __builtin_nontemporal_store(v7_, gdst + lane + 448);
            __builtin_nontemporal_store(v8_, gdst + lane + 512);
            __builtin_nontemporal_store(v9_, gdst + lane + 576);
            __builtin_nontemporal_store(va_, gdst + lane + 640);
            if (extra) __builtin_nontemporal_store(vb_, gdst + lane + 704);
        } else {
            const int nch = (SPW * T) >> 2;
            for (int i = lane; i < nch; i += 64) {
                f32x4 v = lsrc[i];
                __builtin_nontemporal_store(v, gdst + i);
            }
        }
    } else {
        // ---- tail path (N % SPW != 0): direct cached stores ----
        float* obase = out + (size_t)wbase * T;
        for (int j = 0; j < send; ++j) {
            float sc  = rlane(cc,  j), sm  = rlane(cm,  j);
            float sA0 = rlane(cA0, j), sB0 = rlane(cB0, j);
            float sA1 = rlane(cA1, j), sB1 = rlane(cB1, j);
            float sA2 = rlane(cA2, j), sB2 = rlane(cB2, j);
            float sA3 = rlane(cA3, j), sB3 = rlane(cB3, j);
            float* orow = obase + (size_t)j * T;
            #pragma unroll
            for (int q = 0; q < NPAIR; ++q) {
                f32x2 sig = sp2(sc) + sp2(sm) * tv[q];
                sig += sp2(sA0) * bs[q][0] + sp2(sB0) * bc[q][0];
                sig += sp2(sA1) * bs[q][1] + sp2(sB1) * bc[q][1];
                sig += sp2(sA2) * bs[q][2] + sp2(sB2) * bc[q][2];
                sig += sp2(sA3) * bs[q][3] + sp2(sB3) * bc[q][3];
                const int t = t0 + 128 * q;
                if (full[q]) { orow[t] = sig.x; orow[t + 1] = sig.y; }
                else if (any[q]) { orow[t] = sig.x; }
            }
        }
    }
}

extern "C" void kernel_launch(void* const* d_in, const int* in_sizes, int n_in,
                              void* d_out, int out_size, void* d_ws, size_t ws_size,
                              hipStream_t stream)
{
    const float* time_vector     = (const float*)d_in[0];
    const float* constant_offset = (const float*)d_in[1];
    const float* linear_trend    = (const float*)d_in[2];
    const float* amps            = (const float*)d_in[3];
    const float* phs             = (const float*)d_in[4];
    const float* wgt             = (const float*)d_in[5];
    const float* periods         = (const float*)d_in[6];
    const int*   nbidx           = (const int*)d_in[7];

    int T = in_sizes[0];
    int N = in_sizes[1];
    int K = in_sizes[5] / N;
    float* out = (float*)d_out;

    int grid = (N + SPB - 1) / SPB;
    size_t shmem = (size_t)SPB * T * sizeof(float);
    if (T == 365) {
        fused_v17<365><<<grid, BLOCK, shmem, stream>>>(
            time_vector, constant_offset, linear_trend, amps, phs, wgt,
            periods, nbidx, out, N, T, K);
    } else {
        fused_v17<0><<<grid, BLOCK, shmem, stream>>>(
            time_vector, constant_offset, linear_trend, amps, phs, wgt,
            periods, nbidx, out, N, T, K);
    }
}